// Round 8
// baseline (1426.039 us; speedup 1.0000x reference)
//
#include <hip/hip_runtime.h>

#define NB 16
#define NN 8192
#define NS 1024
#define NK 32
#define NR (NB*NS*NK)   // 524288 rows through the MLP

#define NFPS 16          // fps blocks (one per batch)
#define NWORK 240        // persistent worker blocks (ballquery + stats1)
#define NWAVES (NWORK*8) // 1920 worker waves
#define NBLK (NR/256)    // 2048 MLP blocks

// pack two f32 -> two bf16 (RNE) in one uint (low = first)
static __device__ __forceinline__ unsigned pack_bf2(float a, float b) {
  unsigned ua = __float_as_uint(a), ub = __float_as_uint(b);
  ua += 0x7fffu + ((ua >> 16) & 1u);
  ub += 0x7fffu + ((ub >> 16) & 1u);
  return (ua >> 16) | (ub & 0xffff0000u);
}
static __device__ __forceinline__ float bf_lo(unsigned u) { return __uint_as_float(u << 16); }
static __device__ __forceinline__ float bf_hi(unsigned u) { return __uint_as_float(u & 0xffff0000u); }

// ---- DPP wave-64 reductions (VALU pipe; proven bit-exact round 6) ----
template<int CTRL>
static __device__ __forceinline__ float dppmaxf(float v) {
  int m = __builtin_amdgcn_update_dpp(0, __float_as_int(v), CTRL, 0xf, 0xf, true);
  return fmaxf(v, __int_as_float(m));
}
template<int CTRL>
static __device__ __forceinline__ unsigned dppmaxu(unsigned v) {
  unsigned m = (unsigned)__builtin_amdgcn_update_dpp(0, (int)v, CTRL, 0xf, 0xf, true);
  return v > m ? v : m;
}

// ---------------------------------------------------------------------------
// Inline BN finalize, run by the LAST block (atomic ticket). Fixed slice
// partition -> deterministic f64 sums. Same mean/var/ab formula as the
// previous standalone finalize_kernel.
// ---------------------------------------------------------------------------
__device__ __forceinline__ void fin_inline(const float* __restrict__ part, int nrows,
                                           int rowstride, int C, int nsl,
                                           const float* __restrict__ g,
                                           const float* __restrict__ be,
                                           float* __restrict__ ab,
                                           double* __restrict__ ds,
                                           double* __restrict__ dq) {
  const int t = threadIdx.x;
  const int c = t % C;
  const int slice = t / C;
  const int per = nrows / nsl;
  const int qo = rowstride >> 1;
  if (slice < nsl) {
    double s = 0.0, q = 0.0;
    const int r0 = slice * per;
    for (int i = 0; i < per; ++i) {
      const size_t r = (size_t)(r0 + i) * rowstride;
      s += (double)part[r + c];
      q += (double)part[r + qo + c];
    }
    ds[slice*C + c] = s;
    dq[slice*C + c] = q;
  }
  __syncthreads();
  if (t < C) {
    double S = 0.0, Q = 0.0;
    for (int i = 0; i < nsl; ++i) { S += ds[i*C + t]; Q += dq[i*C + t]; }
    double mean = S / (double)NR;
    double var  = Q / (double)NR - mean*mean;
    double inv  = 1.0 / sqrt(var + 1e-5);
    double gg   = (double)g[t];
    ab[t]     = (float)(gg * inv);
    ab[C + t] = (float)((double)be[t] - mean * gg * inv);
  }
}

// ---------------------------------------------------------------------------
// FUSED fps + ballquery + stats1 (round-6 DPP version, proven 974us) + ticket:
// last worker block (of 240) inlines fin1 -> ab1, removing the standalone
// finalize launch. Ticket visibility = the round-2/3 gridbar pattern
// (stores -> __syncthreads [vmcnt-drain] -> t0 ACQ_REL agent RMW -> last
// block's acquire), harness-proven cross-XCD. No spin in the ticket ->
// deadlock-impossible.
// ---------------------------------------------------------------------------
__global__ __launch_bounds__(512, 1) void fps_bq_s1_kernel(
    const float* __restrict__ xyz, const float* __restrict__ pts,
    const float* __restrict__ w1,  const float* __restrict__ b1,
    const float* __restrict__ g1,  const float* __restrict__ be1,
    float* __restrict__ new_xyz,   float* __restrict__ x0,
    float* __restrict__ part,      float* __restrict__ ab1,
    unsigned* __restrict__ tick)
{
  __shared__ float sx[NN], sy[NN], sz[NN];
  __shared__ unsigned long long s_wb[2][8];
  __shared__ double dfs[512], dfq[512];   // fin1 scratch (dedicated, no aliasing)
  __shared__ int s_flag;

  if (blockIdx.x < NFPS) {
    // ------------------------- FPS producer (bit-exact, DO NOT TOUCH) ------
    const int b = blockIdx.x;
    const int t = threadIdx.x;
    const int lane = t & 63;
    const int wv = t >> 6;
    const float* base = xyz + (size_t)b * NN * 3;

    float px[16], py[16], pz[16], dist[16];
#pragma unroll
    for (int j = 0; j < 16; ++j) {
      int p = j * 512 + t;
      float x = base[p*3+0], y = base[p*3+1], z = base[p*3+2];
      px[j] = x; py[j] = y; pz[j] = z; dist[j] = 1e10f;
      sx[p] = x; sy[p] = y; sz[p] = z;
    }
    __syncthreads();

    float cx = sx[0], cy = sy[0], cz = sz[0];
    unsigned* outp = (unsigned*)(new_xyz + (size_t)b * NS * 3);
    if (t == 0) {
      __hip_atomic_store(outp+0, __float_as_uint(cx), __ATOMIC_RELAXED, __HIP_MEMORY_SCOPE_AGENT);
      __hip_atomic_store(outp+1, __float_as_uint(cy), __ATOMIC_RELAXED, __HIP_MEMORY_SCOPE_AGENT);
      __hip_atomic_store(outp+2, __float_as_uint(cz), __ATOMIC_RELAXED, __HIP_MEMORY_SCOPE_AGENT);
    }

    for (int s = 1; s < NS; ++s) {
      const int par = s & 1;
      float bestv = -1.0f;
      int bj = 0;
#pragma unroll
      for (int j = 0; j < 16; ++j) {
        float dx = px[j]-cx, dy = py[j]-cy, dz = pz[j]-cz;
        float d = __fadd_rn(__fadd_rn(__fmul_rn(dx,dx),__fmul_rn(dy,dy)),__fmul_rn(dz,dz));
        float nd = fminf(dist[j], d);
        dist[j] = nd;
        if (nd > bestv) { bestv = nd; bj = j; }   // smallest j at the max
      }
      float wm = bestv;
      wm = dppmaxf<0x111>(wm);   // row_shr:1
      wm = dppmaxf<0x112>(wm);   // row_shr:2
      wm = dppmaxf<0x114>(wm);   // row_shr:4
      wm = dppmaxf<0x118>(wm);   // row_shr:8
      wm = dppmaxf<0x142>(wm);   // row_bcast15
      wm = dppmaxf<0x143>(wm);   // row_bcast31
      const unsigned wmax_bits = (unsigned)__builtin_amdgcn_readlane(__float_as_int(wm), 63);
      const float wmax = __uint_as_float(wmax_bits);
      unsigned enc = (bestv == wmax) ? (unsigned)(8191 - (bj * 512 + t)) : 0u;
      enc = dppmaxu<0x111>(enc);
      enc = dppmaxu<0x112>(enc);
      enc = dppmaxu<0x114>(enc);
      enc = dppmaxu<0x118>(enc);
      enc = dppmaxu<0x142>(enc);
      enc = dppmaxu<0x143>(enc);
      const unsigned widx_enc = (unsigned)__builtin_amdgcn_readlane((int)enc, 63);
      if (lane == 0)
        s_wb[par][wv] = ((unsigned long long)wmax_bits << 32) | widx_enc;
      __syncthreads();
      unsigned long long gk = s_wb[par][0];
#pragma unroll
      for (int i = 1; i < 8; ++i) {
        unsigned long long ki = s_wb[par][i]; if (ki > gk) gk = ki;
      }
      const int bi = 8191 - (int)(gk & 0xffffull);
      cx = sx[bi]; cy = sy[bi]; cz = sz[bi];
      if (t == 0) {
        unsigned* o = outp + s*3;
        __hip_atomic_store(o+0, __float_as_uint(cx), __ATOMIC_RELAXED, __HIP_MEMORY_SCOPE_AGENT);
        __hip_atomic_store(o+1, __float_as_uint(cy), __ATOMIC_RELAXED, __HIP_MEMORY_SCOPE_AGENT);
        __hip_atomic_store(o+2, __float_as_uint(cz), __ATOMIC_RELAXED, __HIP_MEMORY_SCOPE_AGENT);
      }
    }
  } else {
    // --------------------- persistent BQ+stats1 workers ---------------------
    const int wid  = ((int)blockIdx.x - NFPS) * 8 + (threadIdx.x >> 6);
    const int lane = threadIdx.x & 63;
    float wrow[6];
#pragma unroll
    for (int c = 0; c < 6; ++c) wrow[c] = w1[lane*6 + c];
    const float bv = b1[lane];
    const float R2 = 0.04f;
    float itemS = 0.f, itemQ = 0.f;   // per-wave accumulated BN1 partials

    for (int item = wid; item < NB*NS; item += NWAVES) {
      const int s = item >> 4;        // s-major: early centroids first
      const int b = item & 15;
      const int gw = (b << 10) + s;
      const float* base  = xyz + (size_t)b * NN * 3;
      const float* pbase = pts + (size_t)b * NN * 3;
      float* out = x0 + (size_t)gw * (NK*6);

      const unsigned* cp = (const unsigned*)(new_xyz + (size_t)gw * 3);
      float cx, cy, cz;
      for (;;) {
        unsigned ux = __hip_atomic_load(cp+0, __ATOMIC_RELAXED, __HIP_MEMORY_SCOPE_AGENT);
        unsigned uy = __hip_atomic_load(cp+1, __ATOMIC_RELAXED, __HIP_MEMORY_SCOPE_AGENT);
        unsigned uz = __hip_atomic_load(cp+2, __ATOMIC_RELAXED, __HIP_MEMORY_SCOPE_AGENT);
        if (ux != 0xFFFFFFFFu && uy != 0xFFFFFFFFu && uz != 0xFFFFFFFFu) {
          cx = __uint_as_float(ux); cy = __uint_as_float(uy); cz = __uint_as_float(uz);
          break;
        }
        __builtin_amdgcn_s_sleep(16);
      }

      // ---- ball query (bit-identical numerics) ----
      const float t1 = __fadd_rn(__fadd_rn(__fmul_rn(cx,cx),__fmul_rn(cy,cy)),__fmul_rn(cz,cz));
      int count = 0, pfirst = 0;
      for (int n0 = 0; n0 < NN; n0 += 64) {
        const int p = n0 + lane;
        const float ax = base[p*3], ay = base[p*3+1], az = base[p*3+2];
        const float t2 = __fadd_rn(__fadd_rn(__fmul_rn(ax,ax),__fmul_rn(ay,ay)),__fmul_rn(az,az));
        const float dt = __fmaf_rn(cz, az, __fmaf_rn(cy, ay, __fmul_rn(cx, ax)));
        const float sq = __fadd_rn(__fsub_rn(t1, __fmul_rn(2.0f,dt)), t2);
        const bool keep = !(sq > R2);
        const unsigned long long mask = __ballot(keep);
        const int slot = count + __popcll(mask & ((1ull<<lane)-1ull));
        if (keep && slot < NK) {
          float* o = out + slot*6;
          o[0]=ax-cx; o[1]=ay-cy; o[2]=az-cz;
          o[3]=pbase[p*3]; o[4]=pbase[p*3+1]; o[5]=pbase[p*3+2];
        }
        if (count == 0 && mask != 0ull) pfirst = n0 + (__ffsll((unsigned long long)mask) - 1);
        count += __popcll(mask);
        if (count >= NK) break;
      }
      if (count < NK) {
        const float* fx = base + (size_t)pfirst*3;
        const float* fp = pbase + (size_t)pfirst*3;
        const float a0 = fx[0]-cx, a1 = fx[1]-cy, a2 = fx[2]-cz;
        const float a3 = fp[0], a4 = fp[1], a5 = fp[2];
        for (int sl = count + lane; sl < NK; sl += 64) {
          float* o = out + sl*6;
          o[0]=a0;o[1]=a1;o[2]=a2;o[3]=a3;o[4]=a4;o[5]=a5;
        }
      }

      // ---- stats1 for this item's 32 rows (lane = channel) ----
      __threadfence_block();
      float sAcc = 0.f, qAcc = 0.f;
#pragma unroll 4
      for (int k = 0; k < NK; ++k) {
        const float* row = out + k*6;
        float z = bv;
#pragma unroll
        for (int c = 0; c < 6; ++c) z = fmaf(row[c], wrow[c], z);
        sAcc += z;
        qAcc = fmaf(z, z, qAcc);
      }
      itemS += sAcc;
      itemQ += qAcc;
    }
    // one part row per wave: [1920][128]
    part[(size_t)wid*128 + lane]      = itemS;
    part[(size_t)wid*128 + 64 + lane] = itemQ;

    // ---- ticket: last worker block inlines fin1 -> ab1 ----
    __syncthreads();
    if (threadIdx.x == 0) {
      unsigned old = __hip_atomic_fetch_add(tick, 1u, __ATOMIC_ACQ_REL, __HIP_MEMORY_SCOPE_AGENT);
      s_flag = (old == (unsigned)(NWORK - 1));
    }
    __syncthreads();
    if (s_flag)
      fin_inline(part, NWAVES, 128, 64, 8, g1, be1, ab1, dfs, dfq);
  }
}

// ============================ MLP passes ============================

__device__ __forceinline__ void lean_h1(const float* __restrict__ xr,
                                        const float* __restrict__ w1,
                                        const float* __restrict__ b1,
                                        const float* __restrict__ ab1,
                                        float (&h)[64]) {
  float x[6];
#pragma unroll
  for (int c = 0; c < 6; ++c) x[c] = xr[c];
#pragma unroll
  for (int o = 0; o < 64; ++o) {
    float acc = b1[o];
#pragma unroll
    for (int c = 0; c < 6; ++c) acc = fmaf(x[c], w1[o*6+c], acc);
    h[o] = fmaxf(0.f, fmaf(acc, ab1[o], ab1[64+o]));
  }
}

// ---------------------------------------------------------------------------
// stats2 v2 (round-5 proven) + ticket-inlined fin2 (last of 2048 blocks).
// ---------------------------------------------------------------------------
__global__ __launch_bounds__(256) void stats2_store(const float* __restrict__ x0,
                                                    const float* __restrict__ w1,
                                                    const float* __restrict__ b1,
                                                    const float* __restrict__ ab1,
                                                    const float* __restrict__ w2,
                                                    const float* __restrict__ b2,
                                                    const float* __restrict__ g2,
                                                    const float* __restrict__ be2,
                                                    unsigned* __restrict__ z2u,
                                                    float* __restrict__ part,
                                                    float* __restrict__ ab2,
                                                    unsigned* __restrict__ tick) {
  const int t = threadIdx.x;
  const int lane = t & 63;
  const int wvi = t >> 6;
  __shared__ float hT[4][64*68];       // 69,632 B
  __shared__ float rS[4][64], rQ[4][64];
  __shared__ double dls[256], dlq[256]; // fin2 scratch (dedicated)
  __shared__ int s_last;

  const int row0 = ((int)blockIdx.x*4 + wvi) * 64;
  float* ht = hT[wvi];

  // ---- phase A: lane = row ----
  {
    float h[64];
    lean_h1(x0 + (size_t)(row0 + lane)*6, w1, b1, ab1, h);
    float4* hw = (float4*)(ht + lane*68);
#pragma unroll
    for (int c4 = 0; c4 < 16; ++c4)
      hw[c4] = make_float4(h[4*c4+0], h[4*c4+1], h[4*c4+2], h[4*c4+3]);
  }
  asm volatile("s_waitcnt lgkmcnt(0)" ::: "memory");

  // ---- phase B: lane = output channel o ----
  float w2r[64];
  {
    const float4* wr = (const float4*)(w2 + (size_t)lane*64);
#pragma unroll
    for (int c4 = 0; c4 < 16; ++c4) {
      float4 v = wr[c4];
      w2r[4*c4+0]=v.x; w2r[4*c4+1]=v.y; w2r[4*c4+2]=v.z; w2r[4*c4+3]=v.w;
    }
  }
  const float bz = b2[lane];
  float accS = 0.f, accQ = 0.f;
#pragma unroll 2
  for (int r = 0; r < 64; ++r) {
    const float4* hr = (const float4*)(ht + r*68);
    float z = bz;
#pragma unroll
    for (int c4 = 0; c4 < 16; ++c4) {
      float4 hv = hr[c4];                 // uniform-address broadcast
      z = fmaf(hv.x, w2r[4*c4+0], z);
      z = fmaf(hv.y, w2r[4*c4+1], z);
      z = fmaf(hv.z, w2r[4*c4+2], z);
      z = fmaf(hv.w, w2r[4*c4+3], z);
    }
    accS += z; accQ = fmaf(z, z, accQ);
    const float zp = __shfl_xor(z, 1, 64);
    const unsigned word = (lane & 1) ? pack_bf2(zp, z) : pack_bf2(z, zp);
    if ((lane & 1) == 0)
      z2u[(size_t)(row0 + r)*32 + (lane >> 1)] = word;
  }
  rS[wvi][lane] = accS; rQ[wvi][lane] = accQ;
  __syncthreads();
  if (t < 64)
    part[(size_t)blockIdx.x*128 + t] = rS[0][t]+rS[1][t]+rS[2][t]+rS[3][t];
  else if (t < 128) {
    const int c = t - 64;
    part[(size_t)blockIdx.x*128 + 64 + c] = rQ[0][c]+rQ[1][c]+rQ[2][c]+rQ[3][c];
  }

  // ---- ticket: last block inlines fin2 -> ab2 ----
  __syncthreads();
  if (t == 0) {
    unsigned old = __hip_atomic_fetch_add(tick, 1u, __ATOMIC_ACQ_REL, __HIP_MEMORY_SCOPE_AGENT);
    s_last = (old == (unsigned)(NBLK - 1));
  }
  __syncthreads();
  if (s_last)
    fin_inline(part, NBLK, 128, 64, 4, g2, be2, ab2, dls, dlq);
}

// ---------------------------------------------------------------------------
// stats3 v2 (round-5 proven) + ticket-inlined fin3 (last of 2048 blocks).
// ---------------------------------------------------------------------------
__global__ __launch_bounds__(256) void stats3_fused(const unsigned* __restrict__ z2u,
                                                    const float* __restrict__ ab,
                                                    const float* __restrict__ w,
                                                    const float* __restrict__ bias,
                                                    const float* __restrict__ g3,
                                                    const float* __restrict__ be3,
                                                    float* __restrict__ part,
                                                    float* __restrict__ kmx,
                                                    float* __restrict__ kmn,
                                                    float* __restrict__ ab3,
                                                    unsigned* __restrict__ tick) {
  const int t = threadIdx.x;
  const int lane = t & 63;
  const int wvi = t >> 6;
  __shared__ float hT[4][64*68];       // 69,632 B
  __shared__ float rS[4][128], rQ[4][128];
  __shared__ double dls[256], dlq[256]; // fin3 scratch (dedicated)
  __shared__ int s_last;

  const int row0 = ((int)blockIdx.x*4 + wvi) * 64;
  float* ht = hT[wvi];

  // ---- phase A: lane = row; bn2+relu unpack ----
  {
    const uint4* zr = (const uint4*)(z2u + (size_t)(row0 + lane) * 32);
    float h[64];
#pragma unroll
    for (int i = 0; i < 8; ++i) {
      uint4 v = zr[i];
      const int c = i*8;
      h[c+0]=fmaxf(0.f,fmaf(bf_lo(v.x),ab[c+0],ab[64+c+0]));
      h[c+1]=fmaxf(0.f,fmaf(bf_hi(v.x),ab[c+1],ab[64+c+1]));
      h[c+2]=fmaxf(0.f,fmaf(bf_lo(v.y),ab[c+2],ab[64+c+2]));
      h[c+3]=fmaxf(0.f,fmaf(bf_hi(v.y),ab[c+3],ab[64+c+3]));
      h[c+4]=fmaxf(0.f,fmaf(bf_lo(v.z),ab[c+4],ab[64+c+4]));
      h[c+5]=fmaxf(0.f,fmaf(bf_hi(v.z),ab[c+5],ab[64+c+5]));
      h[c+6]=fmaxf(0.f,fmaf(bf_lo(v.w),ab[c+6],ab[64+c+6]));
      h[c+7]=fmaxf(0.f,fmaf(bf_hi(v.w),ab[c+7],ab[64+c+7]));
    }
    float4* hw = (float4*)(ht + lane*68);
#pragma unroll
    for (int c4 = 0; c4 < 16; ++c4)
      hw[c4] = make_float4(h[4*c4+0], h[4*c4+1], h[4*c4+2], h[4*c4+3]);
  }
  asm volatile("s_waitcnt lgkmcnt(0)" ::: "memory");

  // ---- phase B: lane = output channel; chunks o=lane, o=lane+64 ----
  float w3a[64], w3b[64];
  {
    const float4* wra = (const float4*)(w + (size_t)lane*64);
    const float4* wrb = (const float4*)(w + (size_t)(lane+64)*64);
#pragma unroll
    for (int c4 = 0; c4 < 16; ++c4) {
      float4 va = wra[c4];
      w3a[4*c4+0]=va.x; w3a[4*c4+1]=va.y; w3a[4*c4+2]=va.z; w3a[4*c4+3]=va.w;
      float4 vb = wrb[c4];
      w3b[4*c4+0]=vb.x; w3b[4*c4+1]=vb.y; w3b[4*c4+2]=vb.z; w3b[4*c4+3]=vb.w;
    }
  }
  const float bza = bias[lane], bzb = bias[64+lane];
  float sA = 0.f, qA = 0.f, sB = 0.f, qB = 0.f;
#pragma unroll 1
  for (int g2 = 0; g2 < 2; ++g2) {
    float mA = -1e30f, nA = 1e30f, mB = -1e30f, nB = 1e30f;
#pragma unroll 2
    for (int r = g2*32; r < g2*32 + 32; ++r) {
      const float4* hr = (const float4*)(ht + r*68);
      float za = bza, zb = bzb;
#pragma unroll
      for (int c4 = 0; c4 < 16; ++c4) {
        float4 hv = hr[c4];               // uniform-address broadcast
        za = fmaf(hv.x, w3a[4*c4+0], za);
        za = fmaf(hv.y, w3a[4*c4+1], za);
        za = fmaf(hv.z, w3a[4*c4+2], za);
        za = fmaf(hv.w, w3a[4*c4+3], za);
        zb = fmaf(hv.x, w3b[4*c4+0], zb);
        zb = fmaf(hv.y, w3b[4*c4+1], zb);
        zb = fmaf(hv.z, w3b[4*c4+2], zb);
        zb = fmaf(hv.w, w3b[4*c4+3], zb);
      }
      mA = fmaxf(mA, za); nA = fminf(nA, za); sA += za; qA = fmaf(za, za, qA);
      mB = fmaxf(mB, zb); nB = fminf(nB, zb); sB += zb; qB = fmaf(zb, zb, qB);
    }
    const size_t group = (size_t)(((int)blockIdx.x*4 + wvi)*2 + g2);
    kmx[group*128 + lane]      = mA;
    kmx[group*128 + 64 + lane] = mB;
    kmn[group*128 + lane]      = nA;
    kmn[group*128 + 64 + lane] = nB;
  }
  rS[wvi][lane] = sA; rS[wvi][64+lane] = sB;
  rQ[wvi][lane] = qA; rQ[wvi][64+lane] = qB;
  __syncthreads();
  if (t < 128)
    part[(size_t)blockIdx.x*256 + t] = rS[0][t]+rS[1][t]+rS[2][t]+rS[3][t];
  else {
    const int c = t - 128;
    part[(size_t)blockIdx.x*256 + 128 + c] = rQ[0][c]+rQ[1][c]+rQ[2][c]+rQ[3][c];
  }

  // ---- ticket: last block inlines fin3 -> ab3 ----
  __syncthreads();
  if (t == 0) {
    unsigned old = __hip_atomic_fetch_add(tick, 1u, __ATOMIC_ACQ_REL, __HIP_MEMORY_SCOPE_AGENT);
    s_last = (old == (unsigned)(NBLK - 1));
  }
  __syncthreads();
  if (s_last)
    fin_inline(part, NBLK, 256, 128, 2, g3, be3, ab3, dls, dlq);
}

// bn3 (r7-validated): out = relu(a*sel + b), sel = a>=0 ? kmax : kmin
// 2048 blocks x 256 thr x 4 elems.
__global__ __launch_bounds__(256) void bn3_kernel(const float* __restrict__ kmx,
                                                  const float* __restrict__ kmn,
                                                  const float* __restrict__ ab,
                                                  float* __restrict__ outp) {
  const int t = threadIdx.x;
#pragma unroll
  for (int k = 0; k < 4; ++k) {
    const size_t idx = (size_t)blockIdx.x*1024 + k*256 + t;
    const int c = (int)(idx & 127);
    const float a = ab[c], bsh = ab[128 + c];
    const float v = (a >= 0.f) ? kmx[idx] : kmn[idx];
    outp[idx] = fmaxf(0.f, fmaf(v, a, bsh));
  }
}

// ============================ launcher ============================

extern "C" void kernel_launch(void* const* d_in, const int* in_sizes, int n_in,
                              void* d_out, int out_size, void* d_ws, size_t ws_size,
                              hipStream_t stream) {
  (void)in_sizes; (void)n_in; (void)out_size; (void)ws_size;
  const float* xyz = (const float*)d_in[0];
  const float* pts = (const float*)d_in[1];
  const float* w1  = (const float*)d_in[2];
  const float* b1  = (const float*)d_in[3];
  const float* g1  = (const float*)d_in[4];
  const float* be1 = (const float*)d_in[5];
  const float* w2  = (const float*)d_in[6];
  const float* b2  = (const float*)d_in[7];
  const float* g2  = (const float*)d_in[8];
  const float* be2 = (const float*)d_in[9];
  const float* w3  = (const float*)d_in[10];
  const float* b3  = (const float*)d_in[11];
  const float* g3  = (const float*)d_in[12];
  const float* be3 = (const float*)d_in[13];

  float* out = (float*)d_out;
  float* new_xyz    = out;
  float* new_points = out + NB*NS*3;

  // ws: x0 12.6MB | part 8.4MB | ab 2KB | z2u 67MB | kmx 8MB | kmn 8MB | tick
  float* ws = (float*)d_ws;
  float* x0   = ws;                               // NR*6
  float* part = x0 + (size_t)NR*6;                // up to 2048*256 floats
  float* ab   = part + 2097152;                   // 512
  float* ab1  = ab;
  float* ab2  = ab + 128;
  float* ab3  = ab + 256;
  unsigned* z2u = (unsigned*)(ab + 512);          // NR*32 u32
  float* kmx = (float*)(z2u + (size_t)NR*32);     // 16384*128
  float* kmn = kmx + (size_t)16384*128;           // 16384*128
  unsigned* tick = (unsigned*)(kmn + (size_t)16384*128); // 3 u32 tickets

  // NaN-poison new_xyz (publish sentinel) + zero ticket counters.
  (void)hipMemsetAsync(new_xyz, 0xFF, (size_t)NB*NS*3*sizeof(float), stream);
  (void)hipMemsetAsync(tick, 0, 3*sizeof(unsigned), stream);

  // fused FPS + workers (+inline fin1 by last worker block)
  hipLaunchKernelGGL(fps_bq_s1_kernel, dim3(NFPS + NWORK), dim3(512), 0, stream,
                     xyz, pts, w1, b1, g1, be1, new_xyz, x0, part, ab1, tick + 0);

  hipLaunchKernelGGL(stats2_store, dim3(NBLK), dim3(256), 0, stream,
                     x0, w1, b1, ab1, w2, b2, g2, be2, z2u, part, ab2, tick + 1);
  hipLaunchKernelGGL(stats3_fused, dim3(NBLK), dim3(256), 0, stream,
                     z2u, ab2, w3, b3, g3, be3, part, kmx, kmn, ab3, tick + 2);
  hipLaunchKernelGGL(bn3_kernel, dim3(2048), dim3(256), 0, stream, kmx, kmn, ab3, new_points);
}

// Round 9
// 1308.629 us; speedup vs baseline: 1.0897x; 1.0897x over previous
//
#include <hip/hip_runtime.h>

#define NB 16
#define NN 8192
#define NS 1024
#define NK 32
#define NR (NB*NS*NK)   // 524288 rows through the MLP

#define NFPS 16          // fps blocks (one per batch)
#define NWORK 240        // persistent worker blocks (ballquery + stats1)
#define NWAVES (NWORK*8) // 1920 worker waves

// pack two f32 -> two bf16 (RNE) in one uint (low = first)
static __device__ __forceinline__ unsigned pack_bf2(float a, float b) {
  unsigned ua = __float_as_uint(a), ub = __float_as_uint(b);
  ua += 0x7fffu + ((ua >> 16) & 1u);
  ub += 0x7fffu + ((ub >> 16) & 1u);
  return (ua >> 16) | (ub & 0xffff0000u);
}
static __device__ __forceinline__ float bf_lo(unsigned u) { return __uint_as_float(u << 16); }
static __device__ __forceinline__ float bf_hi(unsigned u) { return __uint_as_float(u & 0xffff0000u); }

// ---- DPP wave-64 reductions (VALU pipe; proven bit-exact rounds 6/8) ----
template<int CTRL>
static __device__ __forceinline__ float dppmaxf(float v) {
  int m = __builtin_amdgcn_update_dpp(0, __float_as_int(v), CTRL, 0xf, 0xf, true);
  return fmaxf(v, __int_as_float(m));
}
template<int CTRL>
static __device__ __forceinline__ unsigned dppmaxu(unsigned v) {
  unsigned m = (unsigned)__builtin_amdgcn_update_dpp(0, (int)v, CTRL, 0xf, 0xf, true);
  return v > m ? v : m;
}

// ---------------------------------------------------------------------------
// FUSED fps + ballquery + stats1 (round-6 version, proven 974us, REVERTED
// from round 8's ticket variant: per-block agent-scope release = L2
// writeback per block regressed the chain by ~100us).
// ---------------------------------------------------------------------------
__global__ __launch_bounds__(512, 1) void fps_bq_s1_kernel(
    const float* __restrict__ xyz, const float* __restrict__ pts,
    const float* __restrict__ w1,  const float* __restrict__ b1,
    float* __restrict__ new_xyz,   float* __restrict__ x0,
    float* __restrict__ part)
{
  __shared__ float sx[NN], sy[NN], sz[NN];
  __shared__ unsigned long long s_wb[2][8];

  if (blockIdx.x < NFPS) {
    // ------------------------- FPS producer (bit-exact, DO NOT TOUCH) ------
    const int b = blockIdx.x;
    const int t = threadIdx.x;
    const int lane = t & 63;
    const int wv = t >> 6;
    const float* base = xyz + (size_t)b * NN * 3;

    float px[16], py[16], pz[16], dist[16];
#pragma unroll
    for (int j = 0; j < 16; ++j) {
      int p = j * 512 + t;
      float x = base[p*3+0], y = base[p*3+1], z = base[p*3+2];
      px[j] = x; py[j] = y; pz[j] = z; dist[j] = 1e10f;
      sx[p] = x; sy[p] = y; sz[p] = z;
    }
    __syncthreads();

    float cx = sx[0], cy = sy[0], cz = sz[0];
    unsigned* outp = (unsigned*)(new_xyz + (size_t)b * NS * 3);
    if (t == 0) {
      __hip_atomic_store(outp+0, __float_as_uint(cx), __ATOMIC_RELAXED, __HIP_MEMORY_SCOPE_AGENT);
      __hip_atomic_store(outp+1, __float_as_uint(cy), __ATOMIC_RELAXED, __HIP_MEMORY_SCOPE_AGENT);
      __hip_atomic_store(outp+2, __float_as_uint(cz), __ATOMIC_RELAXED, __HIP_MEMORY_SCOPE_AGENT);
    }

    for (int s = 1; s < NS; ++s) {
      const int par = s & 1;
      float bestv = -1.0f;
      int bj = 0;
#pragma unroll
      for (int j = 0; j < 16; ++j) {
        float dx = px[j]-cx, dy = py[j]-cy, dz = pz[j]-cz;
        float d = __fadd_rn(__fadd_rn(__fmul_rn(dx,dx),__fmul_rn(dy,dy)),__fmul_rn(dz,dz));
        float nd = fminf(dist[j], d);
        dist[j] = nd;
        if (nd > bestv) { bestv = nd; bj = j; }   // smallest j at the max
      }
      float wm = bestv;
      wm = dppmaxf<0x111>(wm);   // row_shr:1
      wm = dppmaxf<0x112>(wm);   // row_shr:2
      wm = dppmaxf<0x114>(wm);   // row_shr:4
      wm = dppmaxf<0x118>(wm);   // row_shr:8
      wm = dppmaxf<0x142>(wm);   // row_bcast15
      wm = dppmaxf<0x143>(wm);   // row_bcast31
      const unsigned wmax_bits = (unsigned)__builtin_amdgcn_readlane(__float_as_int(wm), 63);
      const float wmax = __uint_as_float(wmax_bits);
      unsigned enc = (bestv == wmax) ? (unsigned)(8191 - (bj * 512 + t)) : 0u;
      enc = dppmaxu<0x111>(enc);
      enc = dppmaxu<0x112>(enc);
      enc = dppmaxu<0x114>(enc);
      enc = dppmaxu<0x118>(enc);
      enc = dppmaxu<0x142>(enc);
      enc = dppmaxu<0x143>(enc);
      const unsigned widx_enc = (unsigned)__builtin_amdgcn_readlane((int)enc, 63);
      if (lane == 0)
        s_wb[par][wv] = ((unsigned long long)wmax_bits << 32) | widx_enc;
      __syncthreads();
      unsigned long long gk = s_wb[par][0];
#pragma unroll
      for (int i = 1; i < 8; ++i) {
        unsigned long long ki = s_wb[par][i]; if (ki > gk) gk = ki;
      }
      const int bi = 8191 - (int)(gk & 0xffffull);
      cx = sx[bi]; cy = sy[bi]; cz = sz[bi];
      if (t == 0) {
        unsigned* o = outp + s*3;
        __hip_atomic_store(o+0, __float_as_uint(cx), __ATOMIC_RELAXED, __HIP_MEMORY_SCOPE_AGENT);
        __hip_atomic_store(o+1, __float_as_uint(cy), __ATOMIC_RELAXED, __HIP_MEMORY_SCOPE_AGENT);
        __hip_atomic_store(o+2, __float_as_uint(cz), __ATOMIC_RELAXED, __HIP_MEMORY_SCOPE_AGENT);
      }
    }
  } else {
    // --------------------- persistent BQ+stats1 workers ---------------------
    const int wid  = ((int)blockIdx.x - NFPS) * 8 + (threadIdx.x >> 6);
    const int lane = threadIdx.x & 63;
    float wrow[6];
#pragma unroll
    for (int c = 0; c < 6; ++c) wrow[c] = w1[lane*6 + c];
    const float bv = b1[lane];
    const float R2 = 0.04f;
    float itemS = 0.f, itemQ = 0.f;   // per-wave accumulated BN1 partials

    for (int item = wid; item < NB*NS; item += NWAVES) {
      const int s = item >> 4;        // s-major: early centroids first
      const int b = item & 15;
      const int gw = (b << 10) + s;
      const float* base  = xyz + (size_t)b * NN * 3;
      const float* pbase = pts + (size_t)b * NN * 3;
      float* out = x0 + (size_t)gw * (NK*6);

      const unsigned* cp = (const unsigned*)(new_xyz + (size_t)gw * 3);
      float cx, cy, cz;
      for (;;) {
        unsigned ux = __hip_atomic_load(cp+0, __ATOMIC_RELAXED, __HIP_MEMORY_SCOPE_AGENT);
        unsigned uy = __hip_atomic_load(cp+1, __ATOMIC_RELAXED, __HIP_MEMORY_SCOPE_AGENT);
        unsigned uz = __hip_atomic_load(cp+2, __ATOMIC_RELAXED, __HIP_MEMORY_SCOPE_AGENT);
        if (ux != 0xFFFFFFFFu && uy != 0xFFFFFFFFu && uz != 0xFFFFFFFFu) {
          cx = __uint_as_float(ux); cy = __uint_as_float(uy); cz = __uint_as_float(uz);
          break;
        }
        __builtin_amdgcn_s_sleep(16);
      }

      // ---- ball query (bit-identical numerics) ----
      const float t1 = __fadd_rn(__fadd_rn(__fmul_rn(cx,cx),__fmul_rn(cy,cy)),__fmul_rn(cz,cz));
      int count = 0, pfirst = 0;
      for (int n0 = 0; n0 < NN; n0 += 64) {
        const int p = n0 + lane;
        const float ax = base[p*3], ay = base[p*3+1], az = base[p*3+2];
        const float t2 = __fadd_rn(__fadd_rn(__fmul_rn(ax,ax),__fmul_rn(ay,ay)),__fmul_rn(az,az));
        const float dt = __fmaf_rn(cz, az, __fmaf_rn(cy, ay, __fmul_rn(cx, ax)));
        const float sq = __fadd_rn(__fsub_rn(t1, __fmul_rn(2.0f,dt)), t2);
        const bool keep = !(sq > R2);
        const unsigned long long mask = __ballot(keep);
        const int slot = count + __popcll(mask & ((1ull<<lane)-1ull));
        if (keep && slot < NK) {
          float* o = out + slot*6;
          o[0]=ax-cx; o[1]=ay-cy; o[2]=az-cz;
          o[3]=pbase[p*3]; o[4]=pbase[p*3+1]; o[5]=pbase[p*3+2];
        }
        if (count == 0 && mask != 0ull) pfirst = n0 + (__ffsll((unsigned long long)mask) - 1);
        count += __popcll(mask);
        if (count >= NK) break;
      }
      if (count < NK) {
        const float* fx = base + (size_t)pfirst*3;
        const float* fp = pbase + (size_t)pfirst*3;
        const float a0 = fx[0]-cx, a1 = fx[1]-cy, a2 = fx[2]-cz;
        const float a3 = fp[0], a4 = fp[1], a5 = fp[2];
        for (int sl = count + lane; sl < NK; sl += 64) {
          float* o = out + sl*6;
          o[0]=a0;o[1]=a1;o[2]=a2;o[3]=a3;o[4]=a4;o[5]=a5;
        }
      }

      // ---- stats1 for this item's 32 rows (lane = channel) ----
      __threadfence_block();
      float sAcc = 0.f, qAcc = 0.f;
#pragma unroll 4
      for (int k = 0; k < NK; ++k) {
        const float* row = out + k*6;
        float z = bv;
#pragma unroll
        for (int c = 0; c < 6; ++c) z = fmaf(row[c], wrow[c], z);
        sAcc += z;
        qAcc = fmaf(z, z, qAcc);
      }
      itemS += sAcc;
      itemQ += qAcc;
    }
    // one part row per wave: [1920][128]
    part[(size_t)wid*128 + lane]      = itemS;
    part[(size_t)wid*128 + 64 + lane] = itemQ;
  }
}

// ---------------------------------------------------------------------------
// BN finalize (nrows = partial-row count). Standalone launches are nearly
// free (round-8 lesson: inlining them via agent-scope tickets cost ~100us in
// forced per-block L2 writebacks).
// ---------------------------------------------------------------------------
__global__ __launch_bounds__(256) void finalize_kernel(const float* __restrict__ part,
                                                       int nrows, int rowstride, int C,
                                                       const float* __restrict__ g,
                                                       const float* __restrict__ be,
                                                       float* __restrict__ ab) {
  const int ch = blockIdx.x;
  const int t = threadIdx.x;
  const int qo = rowstride >> 1;
  double s = 0.0, q = 0.0;
  for (int wv = t; wv < nrows; wv += 256) {
    s += (double)part[(size_t)wv*rowstride + ch];
    q += (double)part[(size_t)wv*rowstride + qo + ch];
  }
#pragma unroll
  for (int off = 32; off >= 1; off >>= 1) {
    s += __shfl_down(s, off, 64);
    q += __shfl_down(q, off, 64);
  }
  __shared__ double ls[4], lq[4];
  if ((t & 63) == 0) { ls[t>>6] = s; lq[t>>6] = q; }
  __syncthreads();
  if (t == 0) {
    double S = ls[0]+ls[1]+ls[2]+ls[3];
    double Q = lq[0]+lq[1]+lq[2]+lq[3];
    double mean = S / (double)NR;
    double var  = Q / (double)NR - mean*mean;
    double inv  = 1.0 / sqrt(var + 1e-5);
    double gg   = (double)g[ch];
    ab[ch]     = (float)(gg * inv);
    ab[C + ch] = (float)((double)be[ch] - mean * gg * inv);
  }
}

// ============================ MLP passes ============================

__device__ __forceinline__ void lean_h1(const float* __restrict__ xr,
                                        const float* __restrict__ w1,
                                        const float* __restrict__ b1,
                                        const float* __restrict__ ab1,
                                        float (&h)[64]) {
  float x[6];
#pragma unroll
  for (int c = 0; c < 6; ++c) x[c] = xr[c];
#pragma unroll
  for (int o = 0; o < 64; ++o) {
    float acc = b1[o];
#pragma unroll
    for (int c = 0; c < 6; ++c) acc = fmaf(x[c], w1[o*6+c], acc);
    h[o] = fmaxf(0.f, fmaf(acc, ab1[o], ab1[64+o]));
  }
}

// ---------------------------------------------------------------------------
// stats2 v2 (round-5/6 proven): lane = OUTPUT channel, w2 row register-
// resident; per-wave LDS h-tile (stride 68); bf16 z2 store via lane-pair
// shfl; channel sums in 2 scalar regs.
// ---------------------------------------------------------------------------
__global__ __launch_bounds__(256) void stats2_store(const float* __restrict__ x0,
                                                    const float* __restrict__ w1,
                                                    const float* __restrict__ b1,
                                                    const float* __restrict__ ab1,
                                                    const float* __restrict__ w2,
                                                    const float* __restrict__ b2,
                                                    unsigned* __restrict__ z2u,
                                                    float* __restrict__ part) {
  const int t = threadIdx.x;
  const int lane = t & 63;
  const int wvi = t >> 6;
  __shared__ float hT[4][64*68];       // 69,632 B
  __shared__ float rS[4][64], rQ[4][64];

  const int row0 = ((int)blockIdx.x*4 + wvi) * 64;
  float* ht = hT[wvi];

  // ---- phase A: lane = row ----
  {
    float h[64];
    lean_h1(x0 + (size_t)(row0 + lane)*6, w1, b1, ab1, h);
    float4* hw = (float4*)(ht + lane*68);
#pragma unroll
    for (int c4 = 0; c4 < 16; ++c4)
      hw[c4] = make_float4(h[4*c4+0], h[4*c4+1], h[4*c4+2], h[4*c4+3]);
  }
  asm volatile("s_waitcnt lgkmcnt(0)" ::: "memory");

  // ---- phase B: lane = output channel o ----
  float w2r[64];
  {
    const float4* wr = (const float4*)(w2 + (size_t)lane*64);
#pragma unroll
    for (int c4 = 0; c4 < 16; ++c4) {
      float4 v = wr[c4];
      w2r[4*c4+0]=v.x; w2r[4*c4+1]=v.y; w2r[4*c4+2]=v.z; w2r[4*c4+3]=v.w;
    }
  }
  const float bz = b2[lane];
  float accS = 0.f, accQ = 0.f;
#pragma unroll 2
  for (int r = 0; r < 64; ++r) {
    const float4* hr = (const float4*)(ht + r*68);
    float z = bz;
#pragma unroll
    for (int c4 = 0; c4 < 16; ++c4) {
      float4 hv = hr[c4];                 // uniform-address broadcast
      z = fmaf(hv.x, w2r[4*c4+0], z);
      z = fmaf(hv.y, w2r[4*c4+1], z);
      z = fmaf(hv.z, w2r[4*c4+2], z);
      z = fmaf(hv.w, w2r[4*c4+3], z);
    }
    accS += z; accQ = fmaf(z, z, accQ);
    const float zp = __shfl_xor(z, 1, 64);
    const unsigned word = (lane & 1) ? pack_bf2(zp, z) : pack_bf2(z, zp);
    if ((lane & 1) == 0)
      z2u[(size_t)(row0 + r)*32 + (lane >> 1)] = word;
  }
  rS[wvi][lane] = accS; rQ[wvi][lane] = accQ;
  __syncthreads();
  if (t < 64)
    part[(size_t)blockIdx.x*128 + t] = rS[0][t]+rS[1][t]+rS[2][t]+rS[3][t];
  else if (t < 128) {
    const int c = t - 64;
    part[(size_t)blockIdx.x*128 + 64 + c] = rQ[0][c]+rQ[1][c]+rQ[2][c]+rQ[3][c];
  }
}

// ---------------------------------------------------------------------------
// stats3 v2 (round-5/6 proven): lane holds w3 rows o=lane and o=lane+64 in
// VGPRs; per-wave 64 rows = 2 pool groups; register pooling.
// ---------------------------------------------------------------------------
__global__ __launch_bounds__(256) void stats3_fused(const unsigned* __restrict__ z2u,
                                                    const float* __restrict__ ab,
                                                    const float* __restrict__ w,
                                                    const float* __restrict__ bias,
                                                    float* __restrict__ part,
                                                    float* __restrict__ kmx,
                                                    float* __restrict__ kmn) {
  const int t = threadIdx.x;
  const int lane = t & 63;
  const int wvi = t >> 6;
  __shared__ float hT[4][64*68];       // 69,632 B
  __shared__ float rS[4][128], rQ[4][128];

  const int row0 = ((int)blockIdx.x*4 + wvi) * 64;
  float* ht = hT[wvi];

  // ---- phase A: lane = row; bn2+relu unpack ----
  {
    const uint4* zr = (const uint4*)(z2u + (size_t)(row0 + lane) * 32);
    float h[64];
#pragma unroll
    for (int i = 0; i < 8; ++i) {
      uint4 v = zr[i];
      const int c = i*8;
      h[c+0]=fmaxf(0.f,fmaf(bf_lo(v.x),ab[c+0],ab[64+c+0]));
      h[c+1]=fmaxf(0.f,fmaf(bf_hi(v.x),ab[c+1],ab[64+c+1]));
      h[c+2]=fmaxf(0.f,fmaf(bf_lo(v.y),ab[c+2],ab[64+c+2]));
      h[c+3]=fmaxf(0.f,fmaf(bf_hi(v.y),ab[c+3],ab[64+c+3]));
      h[c+4]=fmaxf(0.f,fmaf(bf_lo(v.z),ab[c+4],ab[64+c+4]));
      h[c+5]=fmaxf(0.f,fmaf(bf_hi(v.z),ab[c+5],ab[64+c+5]));
      h[c+6]=fmaxf(0.f,fmaf(bf_lo(v.w),ab[c+6],ab[64+c+6]));
      h[c+7]=fmaxf(0.f,fmaf(bf_hi(v.w),ab[c+7],ab[64+c+7]));
    }
    float4* hw = (float4*)(ht + lane*68);
#pragma unroll
    for (int c4 = 0; c4 < 16; ++c4)
      hw[c4] = make_float4(h[4*c4+0], h[4*c4+1], h[4*c4+2], h[4*c4+3]);
  }
  asm volatile("s_waitcnt lgkmcnt(0)" ::: "memory");

  // ---- phase B: lane = output channel; chunks o=lane, o=lane+64 ----
  float w3a[64], w3b[64];
  {
    const float4* wra = (const float4*)(w + (size_t)lane*64);
    const float4* wrb = (const float4*)(w + (size_t)(lane+64)*64);
#pragma unroll
    for (int c4 = 0; c4 < 16; ++c4) {
      float4 va = wra[c4];
      w3a[4*c4+0]=va.x; w3a[4*c4+1]=va.y; w3a[4*c4+2]=va.z; w3a[4*c4+3]=va.w;
      float4 vb = wrb[c4];
      w3b[4*c4+0]=vb.x; w3b[4*c4+1]=vb.y; w3b[4*c4+2]=vb.z; w3b[4*c4+3]=vb.w;
    }
  }
  const float bza = bias[lane], bzb = bias[64+lane];
  float sA = 0.f, qA = 0.f, sB = 0.f, qB = 0.f;
#pragma unroll 1
  for (int g2 = 0; g2 < 2; ++g2) {
    float mA = -1e30f, nA = 1e30f, mB = -1e30f, nB = 1e30f;
#pragma unroll 2
    for (int r = g2*32; r < g2*32 + 32; ++r) {
      const float4* hr = (const float4*)(ht + r*68);
      float za = bza, zb = bzb;
#pragma unroll
      for (int c4 = 0; c4 < 16; ++c4) {
        float4 hv = hr[c4];               // uniform-address broadcast
        za = fmaf(hv.x, w3a[4*c4+0], za);
        za = fmaf(hv.y, w3a[4*c4+1], za);
        za = fmaf(hv.z, w3a[4*c4+2], za);
        za = fmaf(hv.w, w3a[4*c4+3], za);
        zb = fmaf(hv.x, w3b[4*c4+0], zb);
        zb = fmaf(hv.y, w3b[4*c4+1], zb);
        zb = fmaf(hv.z, w3b[4*c4+2], zb);
        zb = fmaf(hv.w, w3b[4*c4+3], zb);
      }
      mA = fmaxf(mA, za); nA = fminf(nA, za); sA += za; qA = fmaf(za, za, qA);
      mB = fmaxf(mB, zb); nB = fminf(nB, zb); sB += zb; qB = fmaf(zb, zb, qB);
    }
    const size_t group = (size_t)(((int)blockIdx.x*4 + wvi)*2 + g2);
    kmx[group*128 + lane]      = mA;
    kmx[group*128 + 64 + lane] = mB;
    kmn[group*128 + lane]      = nA;
    kmn[group*128 + 64 + lane] = nB;
  }
  rS[wvi][lane] = sA; rS[wvi][64+lane] = sB;
  rQ[wvi][lane] = qA; rQ[wvi][64+lane] = qB;
  __syncthreads();
  if (t < 128)
    part[(size_t)blockIdx.x*256 + t] = rS[0][t]+rS[1][t]+rS[2][t]+rS[3][t];
  else {
    const int c = t - 128;
    part[(size_t)blockIdx.x*256 + 128 + c] = rQ[0][c]+rQ[1][c]+rQ[2][c]+rQ[3][c];
  }
}

// bn3: out = relu(a*sel + b), sel = a>=0 ? kmax : kmin
// 2048 blocks x 256 thr x 4 elems (reshape passed in round 8).
__global__ __launch_bounds__(256) void bn3_kernel(const float* __restrict__ kmx,
                                                  const float* __restrict__ kmn,
                                                  const float* __restrict__ ab,
                                                  float* __restrict__ outp) {
  const int t = threadIdx.x;
#pragma unroll
  for (int k = 0; k < 4; ++k) {
    const size_t idx = (size_t)blockIdx.x*1024 + k*256 + t;
    const int c = (int)(idx & 127);
    const float a = ab[c], bsh = ab[128 + c];
    const float v = (a >= 0.f) ? kmx[idx] : kmn[idx];
    outp[idx] = fmaxf(0.f, fmaf(v, a, bsh));
  }
}

// ============================ launcher ============================

extern "C" void kernel_launch(void* const* d_in, const int* in_sizes, int n_in,
                              void* d_out, int out_size, void* d_ws, size_t ws_size,
                              hipStream_t stream) {
  (void)in_sizes; (void)n_in; (void)out_size; (void)ws_size;
  const float* xyz = (const float*)d_in[0];
  const float* pts = (const float*)d_in[1];
  const float* w1  = (const float*)d_in[2];
  const float* b1  = (const float*)d_in[3];
  const float* g1  = (const float*)d_in[4];
  const float* be1 = (const float*)d_in[5];
  const float* w2  = (const float*)d_in[6];
  const float* b2  = (const float*)d_in[7];
  const float* g2  = (const float*)d_in[8];
  const float* be2 = (const float*)d_in[9];
  const float* w3  = (const float*)d_in[10];
  const float* b3  = (const float*)d_in[11];
  const float* g3  = (const float*)d_in[12];
  const float* be3 = (const float*)d_in[13];

  float* out = (float*)d_out;
  float* new_xyz    = out;
  float* new_points = out + NB*NS*3;

  // ws: x0 12.6MB | part 8.4MB | ab 2KB | z2u 67MB | kmx 8MB | kmn 8MB ~ 104MB
  float* ws = (float*)d_ws;
  float* x0   = ws;                               // NR*6
  float* part = x0 + (size_t)NR*6;                // up to 2048*256 floats
  float* ab   = part + 2097152;                   // 512
  float* ab1  = ab;
  float* ab2  = ab + 128;
  float* ab3  = ab + 256;
  unsigned* z2u = (unsigned*)(ab + 512);          // NR*32 u32
  float* kmx = (float*)(z2u + (size_t)NR*32);     // 16384*128
  float* kmn = kmx + (size_t)16384*128;           // 16384*128
  const int NBLK = NR/256;                        // 2048

  // NaN-poison new_xyz: the fused kernel's publish sentinel.
  (void)hipMemsetAsync(new_xyz, 0xFF, (size_t)NB*NS*3*sizeof(float), stream);

  // fused FPS (blocks 0..15) + persistent ballquery/stats1 workers (16..255);
  // part written per-WAVE: [1920][128] (sum | sumsq)
  hipLaunchKernelGGL(fps_bq_s1_kernel, dim3(NFPS + NWORK), dim3(512), 0, stream,
                     xyz, pts, w1, b1, new_xyz, x0, part);

  hipLaunchKernelGGL(finalize_kernel, dim3(64), dim3(256), 0, stream, part, NWAVES, 128, 64, g1, be1, ab1);
  hipLaunchKernelGGL(stats2_store, dim3(NBLK), dim3(256), 0, stream,
                     x0, w1, b1, ab1, w2, b2, z2u, part);
  hipLaunchKernelGGL(finalize_kernel, dim3(64), dim3(256), 0, stream, part, NBLK, 128, 64, g2, be2, ab2);
  hipLaunchKernelGGL(stats3_fused, dim3(NBLK), dim3(256), 0, stream,
                     z2u, ab2, w3, b3, part, kmx, kmn);
  hipLaunchKernelGGL(finalize_kernel, dim3(128), dim3(256), 0, stream, part, NBLK, 256, 128, g3, be3, ab3);
  hipLaunchKernelGGL(bn3_kernel, dim3(2048), dim3(256), 0, stream, kmx, kmn, ab3, new_points);
}